// Round 10
// baseline (1151.135 us; speedup 1.0000x reference)
//
#include <hip/hip_runtime.h>
#include <hip/hip_bf16.h>
#include <math.h>

#define NTOKEN 60697
#define D_MODEL 512
#define NLAYERS 4
#define D_STATE 16
#define D_CONV 4
#define D_INNER 1024
#define DT_RANK 32
#define B_SZ 4
#define SEQ 2048
#define EPS 1e-5f
#define NROWS (B_SZ * SEQ)   // 8192
#define CHUNK 128
#define NCHUNK (SEQ / CHUNK) // 16
#define LOG2E 1.44269504f

typedef __bf16 bf16_t;
typedef __attribute__((ext_vector_type(8))) __bf16 bfx8;
typedef __attribute__((ext_vector_type(4))) __bf16 bfx4;
typedef __attribute__((ext_vector_type(4))) float f32x4;

// ---------------- utilities ----------------

__device__ __forceinline__ float fast_sigmoid(float x) {
    return 1.0f / (1.0f + __expf(-x));
}
__device__ __forceinline__ float silu(float x) {
    return x * fast_sigmoid(x);
}
__device__ __forceinline__ float softplus_f(float x) {
    return (x > 20.0f) ? x : log1pf(__expf(x));
}
__device__ __forceinline__ float exp2_fast(float x) {
    float r;
    asm("v_exp_f32 %0, %1" : "=v"(r) : "v"(x));
    return r;
}
__device__ __forceinline__ unsigned int bf16bits(float v) {
    return (unsigned int)__builtin_bit_cast(unsigned short, (bf16_t)v);
}
__device__ __forceinline__ float lo16f(unsigned int u) {
    return __builtin_bit_cast(float, u << 16);
}
__device__ __forceinline__ float hi16f(unsigned int u) {
    return __builtin_bit_cast(float, u & 0xFFFF0000u);
}

__device__ __forceinline__ void gload_lds16(const void* g, void* l) {
    __builtin_amdgcn_global_load_lds(
        (const __attribute__((address_space(1))) unsigned int*)g,
        (__attribute__((address_space(3))) unsigned int*)l, 16, 0, 0);
}

// butterfly sum over 16-lane group via FUSED v_add_f32_dpp (4 inst); result in all lanes.
__device__ __forceinline__ float dpp_sum16(float p) {
    float t;
    asm("v_add_f32_dpp %0, %1, %1 quad_perm:[1,0,3,2] row_mask:0xf bank_mask:0xf"
        : "=v"(t) : "v"(p));
    asm("v_add_f32_dpp %0, %1, %1 quad_perm:[2,3,0,1] row_mask:0xf bank_mask:0xf"
        : "=v"(p) : "v"(t));
    asm("v_add_f32_dpp %0, %1, %1 row_half_mirror row_mask:0xf bank_mask:0xf"
        : "=v"(t) : "v"(p));
    asm("v_add_f32_dpp %0, %1, %1 row_mirror row_mask:0xf bank_mask:0xf"
        : "=v"(p) : "v"(t));
    return p;
}

// block of 256 threads (4 waves). sbuf must be float[4] shared.
__device__ __forceinline__ float blk_reduce_sum(float x, float* sbuf) {
#pragma unroll
    for (int m = 32; m >= 1; m >>= 1) x += __shfl_xor(x, m);
    int wid = threadIdx.x >> 6;
    if ((threadIdx.x & 63) == 0) sbuf[wid] = x;
    __syncthreads();
    float t = sbuf[0] + sbuf[1] + sbuf[2] + sbuf[3];
    __syncthreads();
    return t;
}

// ---------------- fp32 -> bf16 cast (RNE), vector x4 ----------------
__global__ __launch_bounds__(256) void cast_bf16_kernel(
    const float* __restrict__ in, bf16_t* __restrict__ out, size_t n)
{
    size_t stride = (size_t)gridDim.x * 256 * 4;
    for (size_t i = ((size_t)blockIdx.x * 256 + threadIdx.x) * 4; i < n; i += stride) {
        float4 v = *reinterpret_cast<const float4*>(in + i);
        bfx4 o;
        o[0] = (bf16_t)v.x; o[1] = (bf16_t)v.y;
        o[2] = (bf16_t)v.z; o[3] = (bf16_t)v.w;
        *reinterpret_cast<bfx4*>(out + i) = o;
    }
}

// ---------------- embedding + layernorm ----------------

__global__ __launch_bounds__(256) void embed_ln_kernel(
    const int* __restrict__ src, const float* __restrict__ emb,
    const float* __restrict__ w, const float* __restrict__ b,
    float* __restrict__ R)
{
    __shared__ float sbuf[4];
    int row = blockIdx.x;
    int tok = src[row];
    const float* e = emb + (size_t)tok * D_MODEL;
    int c0 = threadIdx.x, c1 = threadIdx.x + 256;
    float v0 = e[c0], v1 = e[c1];
    float mu = blk_reduce_sum(v0 + v1, sbuf) * (1.0f / D_MODEL);
    float d0 = v0 - mu, d1 = v1 - mu;
    float var = blk_reduce_sum(d0 * d0 + d1 * d1, sbuf) * (1.0f / D_MODEL);
    float rs = rsqrtf(var + EPS);
    size_t base = (size_t)row * D_MODEL;
    R[base + c0] = d0 * rs * w[c0] + b[c0];
    R[base + c1] = d1 * rs * w[c1] + b[c1];
}

__global__ __launch_bounds__(256) void add_ln_kernel(
    float* __restrict__ R, const float* __restrict__ Hadd,
    const float* __restrict__ w, const float* __restrict__ b,
    float* __restrict__ out, bf16_t* __restrict__ outb)
{
    __shared__ float sbuf[4];
    size_t base = (size_t)blockIdx.x * D_MODEL;
    int c0 = threadIdx.x, c1 = c0 + 256;
    float v0 = R[base + c0], v1 = R[base + c1];
    if (Hadd) {
        v0 += Hadd[base + c0];
        v1 += Hadd[base + c1];
        R[base + c0] = v0;
        R[base + c1] = v1;
    }
    float mu = blk_reduce_sum(v0 + v1, sbuf) * (1.0f / D_MODEL);
    float d0 = v0 - mu, d1 = v1 - mu;
    float var = blk_reduce_sum(d0 * d0 + d1 * d1, sbuf) * (1.0f / D_MODEL);
    float rs = rsqrtf(var + EPS);
    float o0 = d0 * rs * w[c0] + b[c0];
    float o1 = d1 * rs * w[c1] + b[c1];
    if (out) {
        out[base + c0] = o0;
        out[base + c1] = o1;
    }
    if (outb) {
        outb[base + c0] = (bf16_t)o0;
        outb[base + c1] = (bf16_t)o1;
    }
}

// ---------------- bf16 MFMA GEMM (NT), 128x128 tile ----------------
// EPI 0: C[row*ldc+col] = v (fp32)
// EPI 2: dt-path: v=softplus(v+bias[col]); pack {bf16(v), bf16(v*x)} pair-interleaved
// EPI 3: split store bf16: col<1024 -> Cxb, else -> Czb
template <int EPI>
__global__ __launch_bounds__(256) void gemm_bf16_nt(
    const bf16_t* __restrict__ A, const bf16_t* __restrict__ B,
    float* __restrict__ C, int ldc, int K, const float* __restrict__ bias,
    const unsigned short* __restrict__ xcb_u16,
    unsigned int* __restrict__ dtx_u32,
    bf16_t* __restrict__ Cxb, bf16_t* __restrict__ Czb)
{
    __shared__ bf16_t As[128 * 32];
    __shared__ bf16_t Bs[128 * 32];
    int tid = threadIdx.x;
    int lane = tid & 63, wid = tid >> 6;
    int m0 = blockIdx.y * 128, n0 = blockIdx.x * 128;
    int wm = (wid >> 1) * 64, wn = (wid & 1) * 64;
    int c_lo = lane & 15;
    int khalf = lane >> 4;

    f32x4 acc[4][4];
#pragma unroll
    for (int i = 0; i < 4; i++)
#pragma unroll
        for (int j = 0; j < 4; j++)
            acc[i][j] = (f32x4){0.f, 0.f, 0.f, 0.f};

    for (int k0 = 0; k0 < K; k0 += 32) {
#pragma unroll
        for (int i = 0; i < 2; i++) {
            int c = i * 256 + tid;
            int row = c >> 2;
            int cb = (c & 3) * 16;
            int ldsoff = (i * 256 + wid * 64) * 16;
            gload_lds16((const char*)A + ((size_t)(m0 + row) * K + k0) * 2 + cb,
                        (char*)As + ldsoff);
            gload_lds16((const char*)B + ((size_t)(n0 + row) * K + k0) * 2 + cb,
                        (char*)Bs + ldsoff);
        }
        __syncthreads();

        bfx8 af[4], bfr[4];
#pragma unroll
        for (int i = 0; i < 4; i++) {
            af[i]  = *reinterpret_cast<const bfx8*>(As + (wm + i * 16 + c_lo) * 32 + khalf * 8);
            bfr[i] = *reinterpret_cast<const bfx8*>(Bs + (wn + i * 16 + c_lo) * 32 + khalf * 8);
        }
#pragma unroll
        for (int i = 0; i < 4; i++)
#pragma unroll
            for (int j = 0; j < 4; j++)
                acc[i][j] = __builtin_amdgcn_mfma_f32_16x16x32_bf16(af[i], bfr[j], acc[i][j], 0, 0, 0);
        __syncthreads();
    }

#pragma unroll
    for (int i = 0; i < 4; i++) {
#pragma unroll
        for (int j = 0; j < 4; j++) {
            int row0 = m0 + wm + i * 16 + khalf * 4;
            int col = n0 + wn + j * 16 + c_lo;
#pragma unroll
            for (int r = 0; r < 4; r++) {
                int row = row0 + r;
                float v = acc[i][j][r];
                if (EPI == 0) {
                    C[(size_t)row * ldc + col] = v;
                } else if (EPI == 2) {
                    v = softplus_f(v + bias[col]);
                    float xf = lo16f((unsigned int)xcb_u16[(size_t)row * D_INNER + col]);
                    unsigned int u = bf16bits(v) | (bf16bits(v * xf) << 16);
                    dtx_u32[(size_t)(row >> 1) * 2048 + col * 2 + (row & 1)] = u;
                } else if (EPI == 3) {
                    if (col < D_INNER) Cxb[(size_t)row * D_INNER + col] = (bf16_t)v;
                    else               Czb[(size_t)row * D_INNER + col - D_INNER] = (bf16_t)v;
                }
            }
        }
    }
}

// ---------------- x_proj GEMM: xdbl = XCb(8192x1024) @ xw^T(64x1024) ----------------
// cols 0..31 -> XDlow bf16; cols 32..63 -> BCb bf16-packed {B,C} pair-interleaved.
__global__ __launch_bounds__(128) void gemm_xp_bf16(
    const bf16_t* __restrict__ A, const bf16_t* __restrict__ Bmat,
    bf16_t* __restrict__ XDlow, unsigned int* __restrict__ BCb, int K)
{
    __shared__ bf16_t As[64 * 32];
    __shared__ bf16_t Bs[64 * 32];
    int tid = threadIdx.x;
    int lane = tid & 63, w = tid >> 6;
    int m0 = blockIdx.x * 64;
    int wr0 = w * 32;
    int c_lo = lane & 15;
    int khalf = lane >> 4;

    f32x4 acc[2][4];
#pragma unroll
    for (int i = 0; i < 2; i++)
#pragma unroll
        for (int j = 0; j < 4; j++)
            acc[i][j] = (f32x4){0.f, 0.f, 0.f, 0.f};

    for (int k0 = 0; k0 < K; k0 += 32) {
#pragma unroll
        for (int call = 0; call < 2; call++) {
            int c = call * 128 + tid;
            int base = (call * 128 + w * 64) * 16;
            gload_lds16((const char*)A + ((size_t)(m0 + (c >> 2)) * K + k0) * 2 + (c & 3) * 16,
                        (char*)As + base);
            gload_lds16((const char*)Bmat + ((size_t)(c >> 2) * K + k0) * 2 + (c & 3) * 16,
                        (char*)Bs + base);
        }
        __syncthreads();

        bfx8 af[2], bfr[4];
#pragma unroll
        for (int i = 0; i < 2; i++)
            af[i] = *reinterpret_cast<const bfx8*>(As + (wr0 + i * 16 + c_lo) * 32 + khalf * 8);
#pragma unroll
        for (int j = 0; j < 4; j++)
            bfr[j] = *reinterpret_cast<const bfx8*>(Bs + (j * 16 + c_lo) * 32 + khalf * 8);
#pragma unroll
        for (int i = 0; i < 2; i++)
#pragma unroll
            for (int j = 0; j < 4; j++)
                acc[i][j] = __builtin_amdgcn_mfma_f32_16x16x32_bf16(af[i], bfr[j], acc[i][j], 0, 0, 0);
        __syncthreads();
    }

#pragma unroll
    for (int i = 0; i < 2; i++) {
        int row0 = m0 + wr0 + i * 16 + khalf * 4;
#pragma unroll
        for (int r = 0; r < 4; r++) {
            int row = row0 + r;
            XDlow[(size_t)row * DT_RANK + c_lo]      = (bf16_t)acc[i][0][r];
            XDlow[(size_t)row * DT_RANK + 16 + c_lo] = (bf16_t)acc[i][1][r];
            unsigned int u = bf16bits(acc[i][2][r]) | (bf16bits(acc[i][3][r]) << 16);
            BCb[(size_t)(row >> 1) * 32 + c_lo * 2 + (row & 1)] = u;
        }
    }
}

// ---------------- causal depthwise conv + silu (bf16 in, x2 vector) ----------------
__global__ __launch_bounds__(256) void conv_silu_kernel(
    const bf16_t* __restrict__ Xrawb, const float* __restrict__ cw,
    const float* __restrict__ cb, bf16_t* __restrict__ XCb)
{
    size_t gid = (size_t)blockIdx.x * 256 + threadIdx.x;   // over NROWS * D_INNER/2
    int dp = (int)(gid & 511);          // d-pair; d = 2dp, 2dp+1
    size_t bt = gid >> 9;
    int t = (int)(bt & (SEQ - 1));
    const unsigned int* Xu = (const unsigned int*)Xrawb;
    int d0 = 2 * dp;
    float a0 = cb[d0], a1 = cb[d0 + 1];
#pragma unroll
    for (int k = 0; k < D_CONV; k++) {
        int tt = t + k - (D_CONV - 1);
        if (tt >= 0) {
            unsigned int u = Xu[(bt + (size_t)(k - (D_CONV - 1))) * 512 + dp];
            a0 += cw[d0 * D_CONV + k] * lo16f(u);
            a1 += cw[(d0 + 1) * D_CONV + k] * hi16f(u);
        }
    }
    unsigned int o = bf16bits(silu(a0)) | (bf16bits(silu(a1)) << 16);
    ((unsigned int*)XCb)[gid] = o;
}

// ---------------- staging for 64-step tiles ----------------
// slot (8KB): [0,4096) dtx: [pair][16 d][2] u32; [4096,8192) bcb: [pair][16 s][2] u32
__device__ __forceinline__ void scan_stage64(
    char* base, const unsigned int* __restrict__ DTXp,
    const unsigned int* __restrict__ BCp, size_t rowpair0, int d0, int tid)
{
    gload_lds16(DTXp + (rowpair0 + (size_t)(tid >> 3)) * 2048 + d0 * 2 + (tid & 7) * 4,
                base + tid * 16);
    gload_lds16(BCp + rowpair0 * 32 + tid * 4, base + 4096 + tid * 16);
}

// ---------------- scan pass A: chunk summaries only ----------------
__global__ __launch_bounds__(256) void scan_pA_kernel(
    const unsigned int* __restrict__ DTXb, const unsigned int* __restrict__ BCb,
    const float* __restrict__ A_log,
    float* __restrict__ DcB, float* __restrict__ UcB)
{
    __shared__ __align__(16) char lds[2][8192];
    const int tid = threadIdx.x;
    const int s = tid & 15, dl = tid >> 4;
    const int b = blockIdx.x >> 6;
    const int d0 = (blockIdx.x & 63) * 16;
    const int c = blockIdx.y;
    const int d = d0 + dl;
    const float Av2 = -__expf(A_log[d * D_STATE + s]) * LOG2E;
    const size_t bbase = (size_t)b * SEQ;
    const int tstart = c * CHUNK;

    float h = 0.f, cum = 0.f;
    scan_stage64(lds[0], DTXb, BCb, (bbase + tstart) >> 1, d0, tid);
    __syncthreads();
    int cur = 0;
    for (int t0 = 0; t0 < CHUNK; t0 += 64) {
        if (t0 + 64 < CHUNK)
            scan_stage64(lds[cur ^ 1], DTXb, BCb, (bbase + tstart + t0 + 64) >> 1, d0, tid);
        const char* L = lds[cur];
#pragma unroll
        for (int kk2 = 0; kk2 < 32; kk2++) {
            uint2 dp = *(const uint2*)(L + kk2 * 128 + dl * 8);
            uint2 bp = *(const uint2*)(L + 4096 + kk2 * 128 + s * 8);
#pragma unroll
            for (int j = 0; j < 2; j++) {
                unsigned int pk = j ? dp.y : dp.x;
                unsigned int bk = j ? bp.y : bp.x;
                float dtv = lo16f(pk);
                float ux  = hi16f(pk);
                float bv  = lo16f(bk);
                float e = exp2_fast(dtv * Av2);
                h = fmaf(e, h, ux * bv);
                cum += dtv;
            }
        }
        __syncthreads();
        cur ^= 1;
    }
    size_t cb64 = ((size_t)c * B_SZ + b) * D_INNER + d;
    UcB[cb64 * 16 + s] = h;
    if (s == 0) DcB[cb64] = cum;
}

// ---------------- scan pass B: prefix recompute + local scan + fused combine ------
__global__ __launch_bounds__(256) void scan_pB_kernel(
    const unsigned int* __restrict__ DTXb, const unsigned int* __restrict__ BCb,
    const float* __restrict__ DcB, const float* __restrict__ UcB,
    const float* __restrict__ A_log,
    const bf16_t* __restrict__ Zbufb, const float* __restrict__ Dskip,
    bf16_t* __restrict__ XCb)
{
    __shared__ __align__(16) char lds[2][8192];
    __shared__ float ytile[32][17];
    const int tid = threadIdx.x;
    const int s = tid & 15, dl = tid >> 4;
    const int b = blockIdx.x >> 6;
    const int d0 = (blockIdx.x & 63) * 16;
    const int c = blockIdx.y;
    const int d = d0 + dl;
    const float Av2 = -__expf(A_log[d * D_STATE + s]) * LOG2E;
    const size_t bbase = (size_t)b * SEQ;
    const int tstart = c * CHUNK;

    scan_stage64(lds[0], DTXb, BCb, (bbase + tstart) >> 1, d0, tid);

    // chunk-start state via prefix over earlier chunks (pA completed before launch)
    float h = 0.f;
    for (int j = 0; j < c; j++) {
        size_t base = ((size_t)j * B_SZ + b) * D_INNER + d;
        h = exp2_fast(Av2 * DcB[base]) * h + UcB[base * 16 + s];
    }

    // combine-phase constants: thread -> (tl, dlo pair) over [32 t][16 d] tile
    const int tl  = tid >> 3;
    const int dlo = (tid * 2) & 15;
    const float dsk0 = Dskip[d0 + dlo];
    const float dsk1 = Dskip[d0 + dlo + 1];

    __syncthreads();
    int cur = 0;
    for (int t0 = 0; t0 < CHUNK; t0 += 64) {
        if (t0 + 64 < CHUNK)
            scan_stage64(lds[cur ^ 1], DTXb, BCb, (bbase + tstart + t0 + 64) >> 1, d0, tid);
        const char* L = lds[cur];
#pragma unroll
        for (int g = 0; g < 2; g++) {           // two 32-step groups per tile
#pragma unroll
            for (int half = 0; half < 2; half++) {  // 16-step sub-groups
                float yhold = 0.f;
#pragma unroll
                for (int k8 = 0; k8 < 8; k8++) {
                    int kk2 = g * 16 + half * 8 + k8;
                    uint2 dp = *(const uint2*)(L + kk2 * 128 + dl * 8);
                    uint2 bp = *(const uint2*)(L + 4096 + kk2 * 128 + s * 8);
#pragma unroll
                    for (int j = 0; j < 2; j++) {
                        unsigned int pk = j ? dp.y : dp.x;
                        unsigned int bk = j ? bp.y : bp.x;
                        float dtv = lo16f(pk);
                        float ux  = hi16f(pk);
                        float bv  = lo16f(bk);
                        float cv  = hi16f(bk);
                        float e = exp2_fast(dtv * Av2);
                        h = fmaf(e, h, ux * bv);
                        float p = dpp_sum16(h * cv);
                        int k16 = k8 * 2 + j;
                        if (s == k16) yhold = p;
                    }
                }
                ytile[half * 16 + s][dl] = yhold;
            }
            __syncthreads();   // ytile ready
            {
                int t = tstart + t0 + g * 32 + tl;
                size_t row = (bbase + t) * (size_t)D_INNER + d0 + dlo;
                float y0 = ytile[tl][dlo];
                float y1 = ytile[tl][dlo + 1];
                unsigned int xw = *(const unsigned int*)(XCb + row);
                unsigned int zw = *(const unsigned int*)(Zbufb + row);
                float g0 = (y0 + lo16f(xw) * dsk0) * silu(lo16f(zw));
                float g1 = (y1 + hi16f(xw) * dsk1) * silu(hi16f(zw));
                unsigned int o = bf16bits(g0) | (bf16bits(g1) << 16);
                *(unsigned int*)(XCb + row) = o;
            }
            __syncthreads();   // ytile consumed
        }
        cur ^= 1;
    }
}

// ---------------- launch ----------------

extern "C" void kernel_launch(void* const* d_in, const int* in_sizes, int n_in,
                              void* d_out, int out_size, void* d_ws, size_t ws_size,
                              hipStream_t stream) {
    const int*   src       = (const int*)d_in[0];
    const float* emb_w     = (const float*)d_in[2];
    const float* enc_ln_w  = (const float*)d_in[3];
    const float* enc_ln_b  = (const float*)d_in[4];
    const float* ln_w      = (const float*)d_in[5];
    const float* ln_b      = (const float*)d_in[6];
    const float* in_proj_w = (const float*)d_in[7];
    const float* conv_w    = (const float*)d_in[8];
    const float* conv_b    = (const float*)d_in[9];
    const float* x_proj_w  = (const float*)d_in[10];
    const float* dt_proj_w = (const float*)d_in[11];
    const float* dt_proj_b = (const float*)d_in[12];
    const float* A_log     = (const float*)d_in[13];
    const float* D_skip    = (const float*)d_in[14];
    const float* out_proj_w= (const float*)d_in[15];
    const float* normf_w   = (const float*)d_in[16];
    const float* normf_b   = (const float*)d_in[17];
    float* out = (float*)d_out;

    // fp32 scratch
    float* R    = (float*)d_ws;
    float* H    = R    + (size_t)NROWS * D_MODEL;
    float* DcB  = H    + (size_t)NROWS * D_MODEL;
    float* UcB  = DcB  + (size_t)NCHUNK * B_SZ * D_INNER;
    // packed scratch
    unsigned int* BCb = (unsigned int*)(UcB + (size_t)NCHUNK * B_SZ * D_INNER * D_STATE);
    unsigned int* DTXb = BCb + (size_t)(NROWS / 2) * 32;
    bf16_t* Hb    = (bf16_t*)(DTXb + (size_t)(NROWS / 2) * 2048);
    bf16_t* Xrawb = Hb    + (size_t)NROWS * D_MODEL;
    bf16_t* Zbufb = Xrawb + (size_t)NROWS * D_INNER;
    bf16_t* XCb   = Zbufb + (size_t)NROWS * D_INNER;
    bf16_t* XDlow = XCb   + (size_t)NROWS * D_INNER;
    bf16_t* Wib   = XDlow + (size_t)NROWS * DT_RANK;
    bf16_t* Wob   = Wib   + (size_t)NLAYERS * 2 * D_INNER * D_MODEL;
    bf16_t* xpb   = Wob   + (size_t)NLAYERS * D_MODEL * D_INNER;
    bf16_t* dtwb  = xpb   + (size_t)NLAYERS * 64 * D_INNER;

    // one-time weight prep
    cast_bf16_kernel<<<2048, 256, 0, stream>>>(in_proj_w, Wib, (size_t)NLAYERS * 2 * D_INNER * D_MODEL);
    cast_bf16_kernel<<<2048, 256, 0, stream>>>(out_proj_w, Wob, (size_t)NLAYERS * D_MODEL * D_INNER);
    cast_bf16_kernel<<<256, 256, 0, stream>>>(x_proj_w, xpb, (size_t)NLAYERS * 64 * D_INNER);
    cast_bf16_kernel<<<128, 256, 0, stream>>>(dt_proj_w, dtwb, (size_t)NLAYERS * D_INNER * DT_RANK);

    embed_ln_kernel<<<NROWS, 256, 0, stream>>>(src, emb_w, enc_ln_w, enc_ln_b, R);

    for (int L = 0; L < NLAYERS; L++) {
        const float* AlogL = A_log + (size_t)L * D_INNER * D_STATE;

        add_ln_kernel<<<NROWS, 256, 0, stream>>>(
            R, (L == 0) ? nullptr : H, ln_w + L * D_MODEL, ln_b + L * D_MODEL,
            nullptr, Hb);

        // in_proj -> Xrawb (x half, bf16), Zbufb (z half, bf16)
        gemm_bf16_nt<3><<<dim3(16, 64), 256, 0, stream>>>(
            Hb, Wib + (size_t)L * 2 * D_INNER * D_MODEL, nullptr, 0, D_MODEL,
            nullptr, nullptr, nullptr, Xrawb, Zbufb);

        conv_silu_kernel<<<(NROWS * D_INNER / 2) / 256, 256, 0, stream>>>(
            Xrawb, conv_w + (size_t)L * D_INNER * D_CONV, conv_b + (size_t)L * D_INNER, XCb);

        // x_proj: dt lowrank (bf16) + B/C bf16-packed pair-interleaved
        gemm_xp_bf16<<<NROWS / 64, 128, 0, stream>>>(
            XCb, xpb + (size_t)L * 64 * D_INNER, XDlow, BCb, D_INNER);

        // dt_proj (K=32) + softplus + pack {dt, dt*x} -> DTXb
        gemm_bf16_nt<2><<<dim3(8, 64), 256, 0, stream>>>(
            XDlow, dtwb + (size_t)L * D_INNER * DT_RANK, nullptr, 0, DT_RANK,
            dt_proj_b + (size_t)L * D_INNER, (const unsigned short*)XCb, DTXb,
            nullptr, nullptr);

        // chunked scan: summaries -> recompute(with prefix)+combine
        scan_pA_kernel<<<dim3(B_SZ * 64, NCHUNK), 256, 0, stream>>>(
            DTXb, BCb, AlogL, DcB, UcB);
        scan_pB_kernel<<<dim3(B_SZ * 64, NCHUNK), 256, 0, stream>>>(
            DTXb, BCb, DcB, UcB, AlogL, Zbufb, D_skip + (size_t)L * D_INNER, XCb);

        // out_proj (128x128 generic, fp32 out)
        gemm_bf16_nt<0><<<dim3(4, 64), 256, 0, stream>>>(
            XCb, Wob + (size_t)L * D_MODEL * D_INNER, H, D_MODEL, D_INNER,
            nullptr, nullptr, nullptr, nullptr, nullptr);
    }

    add_ln_kernel<<<NROWS, 256, 0, stream>>>(R, H, normf_w, normf_b, out, nullptr);
}

// Round 11
// 1133.387 us; speedup vs baseline: 1.0157x; 1.0157x over previous
//
#include <hip/hip_runtime.h>
#include <hip/hip_bf16.h>
#include <math.h>

#define NTOKEN 60697
#define D_MODEL 512
#define NLAYERS 4
#define D_STATE 16
#define D_CONV 4
#define D_INNER 1024
#define DT_RANK 32
#define B_SZ 4
#define SEQ 2048
#define EPS 1e-5f
#define NROWS (B_SZ * SEQ)   // 8192
#define CHUNK 128
#define NCHUNK (SEQ / CHUNK) // 16
#define LOG2E 1.44269504f

typedef __bf16 bf16_t;
typedef __attribute__((ext_vector_type(8))) __bf16 bfx8;
typedef __attribute__((ext_vector_type(4))) __bf16 bfx4;
typedef __attribute__((ext_vector_type(4))) float f32x4;

// ---------------- utilities ----------------

__device__ __forceinline__ float fast_sigmoid(float x) {
    return 1.0f / (1.0f + __expf(-x));
}
__device__ __forceinline__ float silu(float x) {
    return x * fast_sigmoid(x);
}
__device__ __forceinline__ float softplus_f(float x) {
    return (x > 20.0f) ? x : log1pf(__expf(x));
}
__device__ __forceinline__ float exp2_fast(float x) {
    float r;
    asm("v_exp_f32 %0, %1" : "=v"(r) : "v"(x));
    return r;
}
__device__ __forceinline__ unsigned int bf16bits(float v) {
    return (unsigned int)__builtin_bit_cast(unsigned short, (bf16_t)v);
}
__device__ __forceinline__ float lo16f(unsigned int u) {
    return __builtin_bit_cast(float, u << 16);
}
__device__ __forceinline__ float hi16f(unsigned int u) {
    return __builtin_bit_cast(float, u & 0xFFFF0000u);
}

__device__ __forceinline__ void gload_lds16(const void* g, void* l) {
    __builtin_amdgcn_global_load_lds(
        (const __attribute__((address_space(1))) unsigned int*)g,
        (__attribute__((address_space(3))) unsigned int*)l, 16, 0, 0);
}

// DPP fetch within 16-lane row; VALU pipe.
template <int CTRL>
__device__ __forceinline__ float dpp_fetch(float x) {
    int xi = __builtin_bit_cast(int, x);
    int yi = __builtin_amdgcn_update_dpp(0, xi, CTRL, 0xF, 0xF, true);
    return __builtin_bit_cast(float, yi);
}
// ds_swizzle lane-xor (BitMode); LDS pipe, no bank conflicts.
template <int IMM>
__device__ __forceinline__ float ds_swz(float x) {
    int r = __builtin_amdgcn_ds_swizzle(__builtin_bit_cast(int, x), IMM);
    return __builtin_bit_cast(float, r);
}

// Batched transpose-reduce: input p[0..15] (lane s holds s-th component of each
// step's product), output: lane k (within its 16-lane group) returns
// y[k] = sum_s p[k][s]. Same binary summation tree as a butterfly (bit order
// 0,1,2,3) -> bit-identical to per-step dpp_sum16.
__device__ __forceinline__ float transpose_reduce16(const float* p, int s) {
    float q[8];
#pragma unroll
    for (int m = 0; m < 8; m++) {
        float mine  = (s & 1) ? p[2 * m + 1] : p[2 * m];
        float other = (s & 1) ? p[2 * m]     : p[2 * m + 1];
        q[m] = mine + dpp_fetch<0xB1>(other);     // quad_perm xor1
    }
    float r4[4];
#pragma unroll
    for (int m = 0; m < 4; m++) {
        float mine  = (s & 2) ? q[2 * m + 1] : q[2 * m];
        float other = (s & 2) ? q[2 * m]     : q[2 * m + 1];
        r4[m] = mine + dpp_fetch<0x4E>(other);    // quad_perm xor2
    }
    float w[2];
#pragma unroll
    for (int m = 0; m < 2; m++) {
        float mine  = (s & 4) ? r4[2 * m + 1] : r4[2 * m];
        float other = (s & 4) ? r4[2 * m]     : r4[2 * m + 1];
        w[m] = mine + ds_swz<0x101F>(other);      // lane xor4
    }
    float mine  = (s & 8) ? w[1] : w[0];
    float other = (s & 8) ? w[0] : w[1];
    return mine + ds_swz<0x201F>(other);          // lane xor8
}

// block of 256 threads (4 waves). sbuf must be float[4] shared.
__device__ __forceinline__ float blk_reduce_sum(float x, float* sbuf) {
#pragma unroll
    for (int m = 32; m >= 1; m >>= 1) x += __shfl_xor(x, m);
    int wid = threadIdx.x >> 6;
    if ((threadIdx.x & 63) == 0) sbuf[wid] = x;
    __syncthreads();
    float t = sbuf[0] + sbuf[1] + sbuf[2] + sbuf[3];
    __syncthreads();
    return t;
}

// ---------------- fused fp32 -> bf16 cast for 4 weight blobs ----------------
__global__ __launch_bounds__(256) void cast_all_kernel(
    const float* __restrict__ s0, const float* __restrict__ s1,
    const float* __restrict__ s2, const float* __restrict__ s3,
    bf16_t* __restrict__ d0, bf16_t* __restrict__ d1,
    bf16_t* __restrict__ d2, bf16_t* __restrict__ d3,
    size_t n0, size_t n1, size_t n2, size_t n3)
{
    size_t ntot = n0 + n1 + n2 + n3;
    size_t stride = (size_t)gridDim.x * 256 * 4;
    for (size_t i = ((size_t)blockIdx.x * 256 + threadIdx.x) * 4; i < ntot; i += stride) {
        const float* s; bf16_t* dst; size_t off = i;
        if (off < n0) { s = s0; dst = d0; }
        else if ((off -= n0) < n1) { s = s1; dst = d1; }
        else if ((off -= n1) < n2) { s = s2; dst = d2; }
        else { off -= n2; s = s3; dst = d3; }
        float4 v = *reinterpret_cast<const float4*>(s + off);
        bfx4 o;
        o[0] = (bf16_t)v.x; o[1] = (bf16_t)v.y;
        o[2] = (bf16_t)v.z; o[3] = (bf16_t)v.w;
        *reinterpret_cast<bfx4*>(dst + off) = o;
    }
}

// ---------------- embedding + layernorm ----------------

__global__ __launch_bounds__(256) void embed_ln_kernel(
    const int* __restrict__ src, const float* __restrict__ emb,
    const float* __restrict__ w, const float* __restrict__ b,
    float* __restrict__ R)
{
    __shared__ float sbuf[4];
    int row = blockIdx.x;
    int tok = src[row];
    const float* e = emb + (size_t)tok * D_MODEL;
    int c0 = threadIdx.x, c1 = threadIdx.x + 256;
    float v0 = e[c0], v1 = e[c1];
    float mu = blk_reduce_sum(v0 + v1, sbuf) * (1.0f / D_MODEL);
    float d0 = v0 - mu, d1 = v1 - mu;
    float var = blk_reduce_sum(d0 * d0 + d1 * d1, sbuf) * (1.0f / D_MODEL);
    float rs = rsqrtf(var + EPS);
    size_t base = (size_t)row * D_MODEL;
    R[base + c0] = d0 * rs * w[c0] + b[c0];
    R[base + c1] = d1 * rs * w[c1] + b[c1];
}

__global__ __launch_bounds__(256) void add_ln_kernel(
    float* __restrict__ R, const float* __restrict__ Hadd,
    const float* __restrict__ w, const float* __restrict__ b,
    float* __restrict__ out, bf16_t* __restrict__ outb)
{
    __shared__ float sbuf[4];
    size_t base = (size_t)blockIdx.x * D_MODEL;
    int c0 = threadIdx.x, c1 = c0 + 256;
    float v0 = R[base + c0], v1 = R[base + c1];
    if (Hadd) {
        v0 += Hadd[base + c0];
        v1 += Hadd[base + c1];
        R[base + c0] = v0;
        R[base + c1] = v1;
    }
    float mu = blk_reduce_sum(v0 + v1, sbuf) * (1.0f / D_MODEL);
    float d0 = v0 - mu, d1 = v1 - mu;
    float var = blk_reduce_sum(d0 * d0 + d1 * d1, sbuf) * (1.0f / D_MODEL);
    float rs = rsqrtf(var + EPS);
    float o0 = d0 * rs * w[c0] + b[c0];
    float o1 = d1 * rs * w[c1] + b[c1];
    if (out) {
        out[base + c0] = o0;
        out[base + c1] = o1;
    }
    if (outb) {
        outb[base + c0] = (bf16_t)o0;
        outb[base + c1] = (bf16_t)o1;
    }
}

// ---------------- bf16 MFMA GEMM (NT), 128x128 tile ----------------
// EPI 0: C[row*ldc+col] = v (fp32)
// EPI 2: dt-path: v=softplus(v+bias[col]); pack {bf16(v), bf16(v*x)} pair-interleaved
// EPI 3: split store bf16: col<1024 -> Cxb, else -> Czb
template <int EPI>
__global__ __launch_bounds__(256) void gemm_bf16_nt(
    const bf16_t* __restrict__ A, const bf16_t* __restrict__ B,
    float* __restrict__ C, int ldc, int K, const float* __restrict__ bias,
    const unsigned short* __restrict__ xcb_u16,
    unsigned int* __restrict__ dtx_u32,
    bf16_t* __restrict__ Cxb, bf16_t* __restrict__ Czb)
{
    __shared__ bf16_t As[128 * 32];
    __shared__ bf16_t Bs[128 * 32];
    int tid = threadIdx.x;
    int lane = tid & 63, wid = tid >> 6;
    int m0 = blockIdx.y * 128, n0 = blockIdx.x * 128;
    int wm = (wid >> 1) * 64, wn = (wid & 1) * 64;
    int c_lo = lane & 15;
    int khalf = lane >> 4;

    f32x4 acc[4][4];
#pragma unroll
    for (int i = 0; i < 4; i++)
#pragma unroll
        for (int j = 0; j < 4; j++)
            acc[i][j] = (f32x4){0.f, 0.f, 0.f, 0.f};

    for (int k0 = 0; k0 < K; k0 += 32) {
#pragma unroll
        for (int i = 0; i < 2; i++) {
            int c = i * 256 + tid;
            int row = c >> 2;
            int cb = (c & 3) * 16;
            int ldsoff = (i * 256 + wid * 64) * 16;
            gload_lds16((const char*)A + ((size_t)(m0 + row) * K + k0) * 2 + cb,
                        (char*)As + ldsoff);
            gload_lds16((const char*)B + ((size_t)(n0 + row) * K + k0) * 2 + cb,
                        (char*)Bs + ldsoff);
        }
        __syncthreads();

        bfx8 af[4], bfr[4];
#pragma unroll
        for (int i = 0; i < 4; i++) {
            af[i]  = *reinterpret_cast<const bfx8*>(As + (wm + i * 16 + c_lo) * 32 + khalf * 8);
            bfr[i] = *reinterpret_cast<const bfx8*>(Bs + (wn + i * 16 + c_lo) * 32 + khalf * 8);
        }
#pragma unroll
        for (int i = 0; i < 4; i++)
#pragma unroll
            for (int j = 0; j < 4; j++)
                acc[i][j] = __builtin_amdgcn_mfma_f32_16x16x32_bf16(af[i], bfr[j], acc[i][j], 0, 0, 0);
        __syncthreads();
    }

#pragma unroll
    for (int i = 0; i < 4; i++) {
#pragma unroll
        for (int j = 0; j < 4; j++) {
            int row0 = m0 + wm + i * 16 + khalf * 4;
            int col = n0 + wn + j * 16 + c_lo;
#pragma unroll
            for (int r = 0; r < 4; r++) {
                int row = row0 + r;
                float v = acc[i][j][r];
                if (EPI == 0) {
                    C[(size_t)row * ldc + col] = v;
                } else if (EPI == 2) {
                    v = softplus_f(v + bias[col]);
                    float xf = lo16f((unsigned int)xcb_u16[(size_t)row * D_INNER + col]);
                    unsigned int u = bf16bits(v) | (bf16bits(v * xf) << 16);
                    dtx_u32[(size_t)(row >> 1) * 2048 + col * 2 + (row & 1)] = u;
                } else if (EPI == 3) {
                    if (col < D_INNER) Cxb[(size_t)row * D_INNER + col] = (bf16_t)v;
                    else               Czb[(size_t)row * D_INNER + col - D_INNER] = (bf16_t)v;
                }
            }
        }
    }
}

// ---------------- x_proj GEMM: xdbl = XCb(8192x1024) @ xw^T(64x1024) ----------------
// cols 0..31 -> XDlow bf16; cols 32..63 -> BCb bf16-packed {B,C} pair-interleaved.
__global__ __launch_bounds__(128) void gemm_xp_bf16(
    const bf16_t* __restrict__ A, const bf16_t* __restrict__ Bmat,
    bf16_t* __restrict__ XDlow, unsigned int* __restrict__ BCb, int K)
{
    __shared__ bf16_t As[64 * 32];
    __shared__ bf16_t Bs[64 * 32];
    int tid = threadIdx.x;
    int lane = tid & 63, w = tid >> 6;
    int m0 = blockIdx.x * 64;
    int wr0 = w * 32;
    int c_lo = lane & 15;
    int khalf = lane >> 4;

    f32x4 acc[2][4];
#pragma unroll
    for (int i = 0; i < 2; i++)
#pragma unroll
        for (int j = 0; j < 4; j++)
            acc[i][j] = (f32x4){0.f, 0.f, 0.f, 0.f};

    for (int k0 = 0; k0 < K; k0 += 32) {
#pragma unroll
        for (int call = 0; call < 2; call++) {
            int c = call * 128 + tid;
            int base = (call * 128 + w * 64) * 16;
            gload_lds16((const char*)A + ((size_t)(m0 + (c >> 2)) * K + k0) * 2 + (c & 3) * 16,
                        (char*)As + base);
            gload_lds16((const char*)Bmat + ((size_t)(c >> 2) * K + k0) * 2 + (c & 3) * 16,
                        (char*)Bs + base);
        }
        __syncthreads();

        bfx8 af[2], bfr[4];
#pragma unroll
        for (int i = 0; i < 2; i++)
            af[i] = *reinterpret_cast<const bfx8*>(As + (wr0 + i * 16 + c_lo) * 32 + khalf * 8);
#pragma unroll
        for (int j = 0; j < 4; j++)
            bfr[j] = *reinterpret_cast<const bfx8*>(Bs + (j * 16 + c_lo) * 32 + khalf * 8);
#pragma unroll
        for (int i = 0; i < 2; i++)
#pragma unroll
            for (int j = 0; j < 4; j++)
                acc[i][j] = __builtin_amdgcn_mfma_f32_16x16x32_bf16(af[i], bfr[j], acc[i][j], 0, 0, 0);
        __syncthreads();
    }

#pragma unroll
    for (int i = 0; i < 2; i++) {
        int row0 = m0 + wr0 + i * 16 + khalf * 4;
#pragma unroll
        for (int r = 0; r < 4; r++) {
            int row = row0 + r;
            XDlow[(size_t)row * DT_RANK + c_lo]      = (bf16_t)acc[i][0][r];
            XDlow[(size_t)row * DT_RANK + 16 + c_lo] = (bf16_t)acc[i][1][r];
            unsigned int u = bf16bits(acc[i][2][r]) | (bf16bits(acc[i][3][r]) << 16);
            BCb[(size_t)(row >> 1) * 32 + c_lo * 2 + (row & 1)] = u;
        }
    }
}

// ---------------- causal depthwise conv + silu (bf16 in, x2 vector) ----------------
__global__ __launch_bounds__(256) void conv_silu_kernel(
    const bf16_t* __restrict__ Xrawb, const float* __restrict__ cw,
    const float* __restrict__ cb, bf16_t* __restrict__ XCb)
{
    size_t gid = (size_t)blockIdx.x * 256 + threadIdx.x;   // over NROWS * D_INNER/2
    int dp = (int)(gid & 511);          // d-pair; d = 2dp, 2dp+1
    size_t bt = gid >> 9;
    int t = (int)(bt & (SEQ - 1));
    const unsigned int* Xu = (const unsigned int*)Xrawb;
    int d0 = 2 * dp;
    float a0 = cb[d0], a1 = cb[d0 + 1];
#pragma unroll
    for (int k = 0; k < D_CONV; k++) {
        int tt = t + k - (D_CONV - 1);
        if (tt >= 0) {
            unsigned int u = Xu[(bt + (size_t)(k - (D_CONV - 1))) * 512 + dp];
            a0 += cw[d0 * D_CONV + k] * lo16f(u);
            a1 += cw[(d0 + 1) * D_CONV + k] * hi16f(u);
        }
    }
    unsigned int o = bf16bits(silu(a0)) | (bf16bits(silu(a1)) << 16);
    ((unsigned int*)XCb)[gid] = o;
}

// ---------------- staging for 64-step tiles ----------------
// slot (8KB): [0,4096) dtx: [pair][16 d][2] u32; [4096,8192) bcb: [pair][16 s][2] u32
__device__ __forceinline__ void scan_stage64(
    char* base, const unsigned int* __restrict__ DTXp,
    const unsigned int* __restrict__ BCp, size_t rowpair0, int d0, int tid)
{
    gload_lds16(DTXp + (rowpair0 + (size_t)(tid >> 3)) * 2048 + d0 * 2 + (tid & 7) * 4,
                base + tid * 16);
    gload_lds16(BCp + rowpair0 * 32 + tid * 4, base + 4096 + tid * 16);
}

// ---------------- scan pass A: chunk summaries only ----------------
__global__ __launch_bounds__(256) void scan_pA_kernel(
    const unsigned int* __restrict__ DTXb, const unsigned int* __restrict__ BCb,
    const float* __restrict__ A_log,
    float* __restrict__ DcB, float* __restrict__ UcB)
{
    __shared__ __align__(16) char lds[2][8192];
    const int tid = threadIdx.x;
    const int s = tid & 15, dl = tid >> 4;
    const int b = blockIdx.x >> 6;
    const int d0 = (blockIdx.x & 63) * 16;
    const int c = blockIdx.y;
    const int d = d0 + dl;
    const float Av2 = -__expf(A_log[d * D_STATE + s]) * LOG2E;
    const size_t bbase = (size_t)b * SEQ;
    const int tstart = c * CHUNK;

    float h = 0.f, cum = 0.f;
    scan_stage64(lds[0], DTXb, BCb, (bbase + tstart) >> 1, d0, tid);
    __syncthreads();
    int cur = 0;
    for (int t0 = 0; t0 < CHUNK; t0 += 64) {
        if (t0 + 64 < CHUNK)
            scan_stage64(lds[cur ^ 1], DTXb, BCb, (bbase + tstart + t0 + 64) >> 1, d0, tid);
        const char* L = lds[cur];
#pragma unroll
        for (int kk2 = 0; kk2 < 32; kk2++) {
            uint2 dp = *(const uint2*)(L + kk2 * 128 + dl * 8);
            uint2 bp = *(const uint2*)(L + 4096 + kk2 * 128 + s * 8);
#pragma unroll
            for (int j = 0; j < 2; j++) {
                unsigned int pk = j ? dp.y : dp.x;
                unsigned int bk = j ? bp.y : bp.x;
                float dtv = lo16f(pk);
                float ux  = hi16f(pk);
                float bv  = lo16f(bk);
                float e = exp2_fast(dtv * Av2);
                h = fmaf(e, h, ux * bv);
                cum += dtv;
            }
        }
        __syncthreads();
        cur ^= 1;
    }
    size_t cb64 = ((size_t)c * B_SZ + b) * D_INNER + d;
    UcB[cb64 * 16 + s] = h;
    if (s == 0) DcB[cb64] = cum;
}

// ---------------- scan pass 2: serial chunk-state propagation ----------------
__global__ __launch_bounds__(256) void scan_p2_kernel(
    const float* __restrict__ A_log, const float* __restrict__ DcB,
    const float* __restrict__ UcB, float* __restrict__ HcB)
{
    int tid = threadIdx.x;
    int s = tid & 15, dl = tid >> 4;
    int chain = blockIdx.x * 16 + dl;
    int b = chain >> 10, d = chain & 1023;
    float Av = -__expf(A_log[d * D_STATE + s]);
    float Hv = 0.f;
    for (int c = 0; c < NCHUNK; c++) {
        size_t base = ((size_t)c * B_SZ + b) * D_INNER + d;
        HcB[base * 16 + s] = Hv;   // state at START of chunk c
        Hv = __expf(Av * DcB[base]) * Hv + UcB[base * 16 + s];
    }
}

// ---------------- scan pass B: recompute from chunk-start state, fused combine ----
__global__ __launch_bounds__(256) void scan_pB_kernel(
    const unsigned int* __restrict__ DTXb, const unsigned int* __restrict__ BCb,
    const float* __restrict__ HcB, const float* __restrict__ A_log,
    const bf16_t* __restrict__ Zbufb, const float* __restrict__ Dskip,
    bf16_t* __restrict__ XCb)
{
    __shared__ __align__(16) char lds[2][8192];
    __shared__ float ytile[32][17];
    const int tid = threadIdx.x;
    const int s = tid & 15, dl = tid >> 4;
    const int b = blockIdx.x >> 6;
    const int d0 = (blockIdx.x & 63) * 16;
    const int c = blockIdx.y;
    const int d = d0 + dl;
    const float Av2 = -__expf(A_log[d * D_STATE + s]) * LOG2E;
    const size_t bbase = (size_t)b * SEQ;
    const int tstart = c * CHUNK;

    float h = HcB[(((size_t)c * B_SZ + b) * D_INNER + d) * 16 + s];

    // combine-phase constants: thread -> (tl, dlo pair) over [32 t][16 d] tile
    const int tl  = tid >> 3;
    const int dlo = (tid * 2) & 15;
    const float dsk0 = Dskip[d0 + dlo];
    const float dsk1 = Dskip[d0 + dlo + 1];

    scan_stage64(lds[0], DTXb, BCb, (bbase + tstart) >> 1, d0, tid);
    __syncthreads();
    int cur = 0;
    for (int t0 = 0; t0 < CHUNK; t0 += 64) {
        if (t0 + 64 < CHUNK)
            scan_stage64(lds[cur ^ 1], DTXb, BCb, (bbase + tstart + t0 + 64) >> 1, d0, tid);
        const char* L = lds[cur];
#pragma unroll
        for (int g = 0; g < 2; g++) {           // two 32-step groups per tile
#pragma unroll
            for (int half = 0; half < 2; half++) {  // 16-step sub-groups
                float p[16];
#pragma unroll
                for (int k8 = 0; k8 < 8; k8++) {
                    int kk2 = g * 16 + half * 8 + k8;
                    uint2 dp = *(const uint2*)(L + kk2 * 128 + dl * 8);
                    uint2 bp = *(const uint2*)(L + 4096 + kk2 * 128 + s * 8);
                    {
                        float dtv = lo16f(dp.x), ux = hi16f(dp.x);
                        float bv = lo16f(bp.x), cv = hi16f(bp.x);
                        h = fmaf(exp2_fast(dtv * Av2), h, ux * bv);
                        p[2 * k8] = h * cv;
                    }
                    {
                        float dtv = lo16f(dp.y), ux = hi16f(dp.y);
                        float bv = lo16f(bp.y), cv = hi16f(bp.y);
                        h = fmaf(exp2_fast(dtv * Av2), h, ux * bv);
                        p[2 * k8 + 1] = h * cv;
                    }
                }
                // lane k of each 16-group gets y for step (half*16 + k)
                ytile[half * 16 + s][dl] = transpose_reduce16(p, s);
            }
            __syncthreads();   // ytile ready
            {
                int t = tstart + t0 + g * 32 + tl;
                size_t row = (bbase + t) * (size_t)D_INNER + d0 + dlo;
                float y0 = ytile[tl][dlo];
                float y1 = ytile[tl][dlo + 1];
                unsigned int xw = *(const unsigned int*)(XCb + row);
                unsigned int zw = *(const unsigned int*)(Zbufb + row);
                float g0 = (y0 + lo16f(xw) * dsk0) * silu(lo16f(zw));
                float g1 = (y1 + hi16f(xw) * dsk1) * silu(hi16f(zw));
                unsigned int o = bf16bits(g0) | (bf16bits(g1) << 16);
                *(unsigned int*)(XCb + row) = o;
            }
            __syncthreads();   // ytile consumed
        }
        cur ^= 1;
    }
}

// ---------------- launch ----------------

extern "C" void kernel_launch(void* const* d_in, const int* in_sizes, int n_in,
                              void* d_out, int out_size, void* d_ws, size_t ws_size,
                              hipStream_t stream) {
    const int*   src       = (const int*)d_in[0];
    const float* emb_w     = (const float*)d_in[2];
    const float* enc_ln_w  = (const float*)d_in[3];
    const float* enc_ln_b  = (const float*)d_in[4];
    const float* ln_w      = (const float*)d_in[5];
    const float* ln_b      = (const float*)d_in[6];
    const float* in_proj_w = (const float*)d_in[7];
    const float* conv_w    = (const float*)d_in[8];
    const float* conv_b    = (const float*)d_in[9];
    const float* x_proj_w  = (const float*)d_in[10];
    const float* dt_proj_w = (const float*)d_in[11];
    const float* dt_proj_b = (const float*)d_in[12];
    const float* A_log     = (const float*)d_in[13];
    const float* D_skip    = (const float*)d_in[14];
    const float* out_proj_w= (const float*)d_in[15];
    const float* normf_w   = (const float*)d_in[16];
    const float* normf_b   = (const float*)d_in[17];
    float* out = (float*)d_out;

    // fp32 scratch
    float* R    = (float*)d_ws;
    float* H    = R    + (size_t)NROWS * D_MODEL;
    float* DcB  = H    + (size_t)NROWS * D_MODEL;
    float* UcB  = DcB  + (size_t)NCHUNK * B_SZ * D_INNER;
    float* HcB  = UcB  + (size_t)NCHUNK * B_SZ * D_INNER * D_STATE;
    // packed scratch
    unsigned int* BCb = (unsigned int*)(HcB + (size_t)NCHUNK * B_SZ * D_INNER * D_STATE);
    unsigned int* DTXb = BCb + (size_t)(NROWS / 2) * 32;
    bf16_t* Hb    = (bf16_t*)(DTXb + (size_t)(NROWS / 2) * 2048);
    bf16_t* Xrawb = Hb    + (size_t)NROWS * D_MODEL;
    bf16_t* Zbufb = Xrawb + (size_t)NROWS * D_INNER;
    bf16_t* XCb   = Zbufb + (size_t)NROWS * D_INNER;
    bf16_t* XDlow = XCb   + (size_t)NROWS * D_INNER;
    bf16_t* Wib   = XDlow + (size_t)NROWS * DT_RANK;
    bf16_t* Wob   = Wib   + (size_t)NLAYERS * 2 * D_INNER * D_MODEL;
    bf16_t* xpb   = Wob   + (size_t)NLAYERS * D_MODEL * D_INNER;
    bf16_t* dtwb  = xpb   + (size_t)NLAYERS * 64 * D_INNER;

    // one-time weight prep (single fused cast kernel)
    cast_all_kernel<<<2048, 256, 0, stream>>>(
        in_proj_w, out_proj_w, x_proj_w, dt_proj_w,
        Wib, Wob, xpb, dtwb,
        (size_t)NLAYERS * 2 * D_INNER * D_MODEL,
        (size_t)NLAYERS * D_MODEL * D_INNER,
        (size_t)NLAYERS * 64 * D_INNER,
        (size_t)NLAYERS * D_INNER * DT_RANK);

    embed_ln_kernel<<<NROWS, 256, 0, stream>>>(src, emb_w, enc_ln_w, enc_ln_b, R);

    for (int L = 0; L < NLAYERS; L++) {
        const float* AlogL = A_log + (size_t)L * D_INNER * D_STATE;

        add_ln_kernel<<<NROWS, 256, 0, stream>>>(
            R, (L == 0) ? nullptr : H, ln_w + L * D_MODEL, ln_b + L * D_MODEL,
            nullptr, Hb);

        // in_proj -> Xrawb (x half, bf16), Zbufb (z half, bf16)
        gemm_bf16_nt<3><<<dim3(16, 64), 256, 0, stream>>>(
            Hb, Wib + (size_t)L * 2 * D_INNER * D_MODEL, nullptr, 0, D_MODEL,
            nullptr, nullptr, nullptr, Xrawb, Zbufb);

        conv_silu_kernel<<<(NROWS * D_INNER / 2) / 256, 256, 0, stream>>>(
            Xrawb, conv_w + (size_t)L * D_INNER * D_CONV, conv_b + (size_t)L * D_INNER, XCb);

        // x_proj: dt lowrank (bf16) + B/C bf16-packed pair-interleaved
        gemm_xp_bf16<<<NROWS / 64, 128, 0, stream>>>(
            XCb, xpb + (size_t)L * 64 * D_INNER, XDlow, BCb, D_INNER);

        // dt_proj (K=32) + softplus + pack {dt, dt*x} -> DTXb
        gemm_bf16_nt<2><<<dim3(8, 64), 256, 0, stream>>>(
            XDlow, dtwb + (size_t)L * D_INNER * DT_RANK, nullptr, 0, DT_RANK,
            dt_proj_b + (size_t)L * D_INNER, (const unsigned short*)XCb, DTXb,
            nullptr, nullptr);

        // chunked scan: summaries -> propagate -> recompute+combine
        scan_pA_kernel<<<dim3(B_SZ * 64, NCHUNK), 256, 0, stream>>>(
            DTXb, BCb, AlogL, DcB, UcB);
        scan_p2_kernel<<<256, 256, 0, stream>>>(AlogL, DcB, UcB, HcB);
        scan_pB_kernel<<<dim3(B_SZ * 64, NCHUNK), 256, 0, stream>>>(
            DTXb, BCb, HcB, AlogL, Zbufb, D_skip + (size_t)L * D_INNER, XCb);

        // out_proj (128x128 generic, fp32 out)
        gemm_bf16_nt<0><<<dim3(4, 64), 256, 0, stream>>>(
            XCb, Wob + (size_t)L * D_MODEL * D_INNER, H, D_MODEL, D_INNER,
            nullptr, nullptr, nullptr, nullptr, nullptr);
    }

    add_ln_kernel<<<NROWS, 256, 0, stream>>>(R, H, normf_w, normf_b, out, nullptr);
}